// Round 11
// baseline (473.226 us; speedup 1.0000x reference)
//
#include <hip/hip_runtime.h>
#include <math.h>

// Problem constants (fixed by the reference)
#define N_NODES 50000
#define E_EDGES 1600000
#define R_REL   50
#define B_BAS   30
#define H_DIM   16
#define C_DIM   4
#define NH      (N_NODES * H_DIM)

// dst slicing for XCD-local scatter writes in k_bucket
#define NSLICE      8
#define SLICE_NODES (N_NODES / NSLICE)   // 6250

// ---------------------------------------------------------------------------
// k_w1: pure streaming w1 precompute (un-fused from hist: the fused kernel's
// waves had to drain their random atomics -- oldest vmcnt entries -- before
// basis-load results could retire, coupling the stream to atomic latency).
//   w1[r][n][h] = sum_b comp1[r][b]*basis1[b][n][h]
// Scalar columns: 48 VGPR, 8 waves/SIMD cap, proven best occupancy (r7 vs
// r8 float4 / r9 float2: occupancy beats bytes-per-instruction here).
// comp1 read directly (thread-uniform -> s_load, SGPR operand to v_fmac).
// ---------------------------------------------------------------------------
__global__ __launch_bounds__(256) void k_w1(const float* __restrict__ basis1,
                                            const float* __restrict__ comp1,
                                            float* __restrict__ w1) {
    const int idx = blockIdx.x * 256 + threadIdx.x;  // < NH exactly (3125 blocks)
    float bv[B_BAS];
#pragma unroll
    for (int b = 0; b < B_BAS; ++b) bv[b] = basis1[b * NH + idx];

    for (int r = 0; r < R_REL; ++r) {
        float acc = 0.f;
#pragma unroll
        for (int b = 0; b < B_BAS; ++b) acc += comp1[r * B_BAS + b] * bv[b];
        w1[(size_t)r * NH + idx] = acc;
    }
}

// ---------------------------------------------------------------------------
// k_hist: standalone per-dst edge histogram (1.6M int atomics, L2-resident
// 200KB table).
// ---------------------------------------------------------------------------
__global__ __launch_bounds__(256) void k_hist(const int* __restrict__ ei,
                                              int* __restrict__ cnt_i) {
    const int e = blockIdx.x * 256 + threadIdx.x;
    if (e < E_EDGES) atomicAdd(&cnt_i[ei[E_EDGES + e]], 1);
}

// ---------------------------------------------------------------------------
// CSR build step 2a: per-block exclusive scan of counts; block totals to bsum
// ---------------------------------------------------------------------------
__global__ __launch_bounds__(256) void k_scan_part(const int* __restrict__ cnt_i,
                                                   int* __restrict__ part,
                                                   int* __restrict__ bsum) {
    const int i = blockIdx.x * 256 + threadIdx.x;
    const int lane = threadIdx.x & 63;
    const int wid = threadIdx.x >> 6;
    const int v = (i < N_NODES) ? cnt_i[i] : 0;
    int s = v;
#pragma unroll
    for (int d = 1; d < 64; d <<= 1) {
        int t = __shfl_up(s, d, 64);
        if (lane >= d) s += t;
    }
    __shared__ int wsum[4];
    if (lane == 63) wsum[wid] = s;
    __syncthreads();
    int woff = 0;
    for (int w = 0; w < wid; ++w) woff += wsum[w];
    if (i < N_NODES) part[i] = s - v + woff;
    if (threadIdx.x == 255) bsum[blockIdx.x] = woff + s;  // block total
}

// ---------------------------------------------------------------------------
// CSR build step 2b: exclusive scan of the 196 block totals (single block).
// Also computes w2 (tiny, independent) to keep it off other kernels.
// ---------------------------------------------------------------------------
__global__ __launch_bounds__(256) void k_scan_tops(const int* __restrict__ bsum,
                                                   int* __restrict__ boff,
                                                   const float* __restrict__ basis2,
                                                   const float* __restrict__ comp2,
                                                   float* __restrict__ w2) {
    const int NB = (N_NODES + 255) / 256;  // 196
    const int lane = threadIdx.x & 63;
    const int wid = threadIdx.x >> 6;
    const int v = (threadIdx.x < NB) ? bsum[threadIdx.x] : 0;
    int s = v;
#pragma unroll
    for (int d = 1; d < 64; d <<= 1) {
        int t = __shfl_up(s, d, 64);
        if (lane >= d) s += t;
    }
    __shared__ int wsum[4];
    if (lane == 63) wsum[wid] = s;
    __syncthreads();
    int woff = 0;
    for (int w = 0; w < wid; ++w) woff += wsum[w];
    if (threadIdx.x < NB) boff[threadIdx.x] = s - v + woff;

    // w2[r][h][c] = sum_b comp2[r][b] * basis2[b][h][c]   (3200 outputs)
    const int HC = H_DIM * C_DIM;  // 64
    for (int idx = threadIdx.x; idx < R_REL * HC; idx += 256) {
        const int r = idx / HC;
        const int hc = idx % HC;
        float acc = 0.f;
#pragma unroll
        for (int b = 0; b < B_BAS; ++b)
            acc += comp2[r * B_BAS + b] * basis2[b * HC + hc];
        w2[idx] = acc;
    }
}

// ---------------------------------------------------------------------------
// CSR build step 2c: combine -> off[] and a working cursor[] copy
// ---------------------------------------------------------------------------
__global__ __launch_bounds__(256) void k_scan_add(const int* __restrict__ part,
                                                  const int* __restrict__ boff,
                                                  int* __restrict__ off,
                                                  int* __restrict__ cursor) {
    const int i = blockIdx.x * 256 + threadIdx.x;
    if (i < N_NODES) {
        const int o = part[i] + boff[blockIdx.x];
        off[i] = o;
        cursor[i] = o;
    }
    if (i == 0) off[N_NODES] = E_EDGES;
}

// ---------------------------------------------------------------------------
// CSR build step 3 (XCD-sliced): scatter packed (src | et<<16) records into
// dst buckets. blockIdx = chunk*8 + slice; a block only handles edges whose
// dst is in its slice's 6250-node range (blockIdx%8 ~ XCD -> rec slice writes
// coalesce in one XCD's L2). Streaming ei/et reads are non-temporal so they
// don't evict the dirty rec lines before neighbors coalesce into them.
// ---------------------------------------------------------------------------
__global__ __launch_bounds__(256) void k_bucket(const int* __restrict__ ei,
                                                const int* __restrict__ et,
                                                int* __restrict__ cursor,
                                                unsigned* __restrict__ rec) {
    const int chunk = blockIdx.x >> 3;
    const int slice = blockIdx.x & (NSLICE - 1);
    const int lo = slice * SLICE_NODES;

    const int e = chunk * 256 + threadIdx.x;
    if (e >= E_EDGES) return;
    const int dst = __builtin_nontemporal_load(&ei[E_EDGES + e]);
    if ((unsigned)(dst - lo) >= (unsigned)SLICE_NODES) return;

    const int src = __builtin_nontemporal_load(&ei[e]);
    const int r = __builtin_nontemporal_load(&et[e]);
    const int pos = atomicAdd(&cursor[dst], 1);
    rec[pos] = (unsigned)src | ((unsigned)r << 16);
}

// ---------------------------------------------------------------------------
// k_agg1x: atomic-free layer-1 aggregation fused with x-epilogue.
// One wave per dst; lanes = (sub=lane>>4) edge-slot x (h=lane&15).
// x[dst][h] = relu( mean_e w1[et][src][h] + root1 + bias1 )
// ---------------------------------------------------------------------------
__global__ __launch_bounds__(256) void k_agg1x(const unsigned* __restrict__ rec,
                                               const int* __restrict__ off,
                                               const float* __restrict__ w1,
                                               const float* __restrict__ root1,
                                               const float* __restrict__ bias1,
                                               float* __restrict__ x) {
    const int wid = threadIdx.x >> 6;
    const int lane = threadIdx.x & 63;
    const int dst = blockIdx.x * 4 + wid;   // grid = 12500, 4 waves/block
    const int h = lane & 15;
    const int sub = lane >> 4;
    const int e0 = off[dst], e1 = off[dst + 1];

    float acc = 0.f;
    for (int e = e0 + sub; e < e1; e += 4) {
        const unsigned p = rec[e];
        const int src = (int)(p & 0xFFFFu);
        const int r = (int)(p >> 16);
        acc += w1[(size_t)r * NH + src * H_DIM + h];
    }
    acc += __shfl_xor(acc, 16, 64);
    acc += __shfl_xor(acc, 32, 64);

    if (sub == 0) {
        const float c = fmaxf((float)(e1 - e0), 1.f);
        const float v = acc / c + root1[dst * H_DIM + h] + bias1[h];
        x[dst * H_DIM + h] = fmaxf(v, 0.f);
    }
}

// ---------------------------------------------------------------------------
// k_agg2out: atomic-free layer-2 aggregation fused with root2 matvec and
// log_softmax. One wave per dst; per edge-slot 16 lanes each do 4 FMAs.
// ---------------------------------------------------------------------------
__global__ __launch_bounds__(256) void k_agg2out(const unsigned* __restrict__ rec,
                                                 const int* __restrict__ off,
                                                 const float* __restrict__ x,
                                                 const float* __restrict__ w2,
                                                 const float* __restrict__ root2,
                                                 const float* __restrict__ bias2,
                                                 float* __restrict__ out) {
    const int wid = threadIdx.x >> 6;
    const int lane = threadIdx.x & 63;
    const int dst = blockIdx.x * 4 + wid;
    const int h = lane & 15;
    const int sub = lane >> 4;
    const int e0 = off[dst], e1 = off[dst + 1];

    float a0 = 0.f, a1 = 0.f, a2 = 0.f, a3 = 0.f;
    for (int e = e0 + sub; e < e1; e += 4) {
        const unsigned p = rec[e];
        const int src = (int)(p & 0xFFFFu);
        const int r = (int)(p >> 16);
        const float xv = x[src * H_DIM + h];
        const float4 w = *(const float4*)(w2 + r * (H_DIM * C_DIM) + h * C_DIM);
        a0 += xv * w.x; a1 += xv * w.y; a2 += xv * w.z; a3 += xv * w.w;
    }
    // reduce over all 64 lanes (sums over both h and edge-slot)
#pragma unroll
    for (int d = 1; d < 64; d <<= 1) {
        a0 += __shfl_xor(a0, d, 64);
        a1 += __shfl_xor(a1, d, 64);
        a2 += __shfl_xor(a2, d, 64);
        a3 += __shfl_xor(a3, d, 64);
    }

    if (lane == 0) {
        const float c = fmaxf((float)(e1 - e0), 1.f);
        float y0 = a0 / c + bias2[0];
        float y1 = a1 / c + bias2[1];
        float y2 = a2 / c + bias2[2];
        float y3 = a3 / c + bias2[3];
#pragma unroll
        for (int hh = 0; hh < H_DIM; ++hh) {
            const float xv = x[dst * H_DIM + hh];
            const float4 w = *(const float4*)(root2 + hh * C_DIM);
            y0 += xv * w.x; y1 += xv * w.y; y2 += xv * w.z; y3 += xv * w.w;
        }
        const float m = fmaxf(fmaxf(y0, y1), fmaxf(y2, y3));
        const float s = expf(y0 - m) + expf(y1 - m) + expf(y2 - m) + expf(y3 - m);
        const float lse = m + logf(s);
        out[dst * 4 + 0] = y0 - lse;
        out[dst * 4 + 1] = y1 - lse;
        out[dst * 4 + 2] = y2 - lse;
        out[dst * 4 + 3] = y3 - lse;
    }
}

// ---------------------------------------------------------------------------
extern "C" void kernel_launch(void* const* d_in, const int* in_sizes, int n_in,
                              void* d_out, int out_size, void* d_ws, size_t ws_size,
                              hipStream_t stream) {
    const int*   edge_index = (const int*)d_in[0];   // [2, E]
    const int*   edge_type  = (const int*)d_in[1];   // [E]
    // d_in[2] = edge_norm (unused by reference)
    const float* basis1 = (const float*)d_in[3];     // [B, N, H]
    const float* comp1  = (const float*)d_in[4];     // [R, B]
    const float* root1  = (const float*)d_in[5];     // [N, H]
    const float* bias1  = (const float*)d_in[6];     // [H]
    const float* basis2 = (const float*)d_in[7];     // [B, H, C]
    const float* comp2  = (const float*)d_in[8];     // [R, B]
    const float* root2  = (const float*)d_in[9];     // [H, C]
    const float* bias2  = (const float*)d_in[10];    // [C]

    float* out = (float*)d_out;

    // ---- workspace layout (16B aligned blocks) ----
    char* ws = (char*)d_ws;
    size_t o = 0;
    auto take = [&](size_t bytes) { char* p = ws + o; o += (bytes + 15) & ~(size_t)15; return p; };

    float*    w1     = (float*)   take((size_t)R_REL * NH * sizeof(float));   // 160.0 MB
    unsigned* rec    = (unsigned*)take((size_t)E_EDGES * sizeof(unsigned));   //   6.4 MB
    float*    x      = (float*)   take((size_t)NH * sizeof(float));           //   3.2 MB
    int*      part   = (int*)x;   // alias: part dead before x is written
    int*      off    = (int*)     take((size_t)(N_NODES + 1) * sizeof(int));
    int*      cnt_i  = (int*)     take((size_t)N_NODES * sizeof(int));
    int*      cursor = (int*)     take((size_t)N_NODES * sizeof(int));
    float*    w2     = (float*)   take((size_t)R_REL * H_DIM * C_DIM * sizeof(float));
    int*      bsum   = (int*)     take(256 * sizeof(int));
    int*      boff   = (int*)     take(256 * sizeof(int));
    (void)ws_size;

    const int NB = (N_NODES + 255) / 256;  // 196 scan blocks

    // zero the histogram (ws is poisoned 0xAA before every timed call)
    hipMemsetAsync(cnt_i, 0, (size_t)N_NODES * sizeof(int), stream);

    // standalone histogram (atomic-bound, short)
    k_hist<<<(E_EDGES + 255) / 256, 256, 0, stream>>>(edge_index, cnt_i);

    // pure streaming w1 precompute
    k_w1<<<NH / 256, 256, 0, stream>>>(basis1, comp1, w1);

    // CSR build: scan (+w2 piggyback) -> bucket (XCD-sliced scatter)
    k_scan_part<<<NB, 256, 0, stream>>>(cnt_i, part, bsum);
    k_scan_tops<<<1, 256, 0, stream>>>(bsum, boff, basis2, comp2, w2);
    k_scan_add<<<NB, 256, 0, stream>>>(part, boff, off, cursor);
    {
        const int chunks = (E_EDGES + 255) / 256;  // 6250
        k_bucket<<<chunks * NSLICE, 256, 0, stream>>>(edge_index, edge_type, cursor, rec);
    }

    // layer 1 (atomic-free) fused with relu/root/bias
    k_agg1x<<<N_NODES / 4, 256, 0, stream>>>(rec, off, w1, root1, bias1, x);

    // layer 2 (atomic-free) fused with root2 matvec + log_softmax
    k_agg2out<<<N_NODES / 4, 256, 0, stream>>>(rec, off, x, w2, root2, bias2, out);
}

// Round 12
// 412.054 us; speedup vs baseline: 1.1485x; 1.1485x over previous
//
#include <hip/hip_runtime.h>
#include <math.h>

// Problem constants (fixed by the reference)
#define N_NODES 50000
#define E_EDGES 1600000
#define R_REL   50
#define B_BAS   30
#define H_DIM   16
#define C_DIM   4
#define NH      (N_NODES * H_DIM)

// dst slicing for XCD-local scatter writes in k_bucket
#define NSLICE      8
#define SLICE_NODES (N_NODES / NSLICE)   // 6250

#define FRONT_BLOCKS (NH / 256)                   // 3125
#define EDGES_PER_FRONT (E_EDGES / FRONT_BLOCKS)  // 512

// ---------------------------------------------------------------------------
// k_front: fused w1 precompute + dst histogram (round-7 structure, proven
// 101us for BOTH; round-11 un-fused = 85us w1 + ~60us hist = net loss).
//   w1[r][n][h] = sum_b comp1[r][b]*basis1[b][n][h]
// comp1 read directly (thread-uniform -> s_load, SGPR operand to v_fmac).
// Scalar columns: 48 VGPR / 43% occupancy beat float2/float4 variants.
// ---------------------------------------------------------------------------
__global__ __launch_bounds__(256) void k_front(const float* __restrict__ basis1,
                                               const float* __restrict__ comp1,
                                               float* __restrict__ w1,
                                               const int* __restrict__ ei,
                                               int* __restrict__ cnt_i) {
    // ---- histogram share: fire-and-forget atomics ----
    {
        const int ebase = blockIdx.x * EDGES_PER_FRONT + threadIdx.x;
        atomicAdd(&cnt_i[ei[E_EDGES + ebase]], 1);
        atomicAdd(&cnt_i[ei[E_EDGES + ebase + 256]], 1);
    }

    // ---- w1 share ----
    const int idx = blockIdx.x * 256 + threadIdx.x;  // < NH exactly
    float bv[B_BAS];
#pragma unroll
    for (int b = 0; b < B_BAS; ++b) bv[b] = basis1[b * NH + idx];

    for (int r = 0; r < R_REL; ++r) {
        float acc = 0.f;
#pragma unroll
        for (int b = 0; b < B_BAS; ++b) acc += comp1[r * B_BAS + b] * bv[b];
        w1[(size_t)r * NH + idx] = acc;
    }
}

// ---------------------------------------------------------------------------
// CSR build step 2a: per-block exclusive scan of counts; block totals to bsum
// ---------------------------------------------------------------------------
__global__ __launch_bounds__(256) void k_scan_part(const int* __restrict__ cnt_i,
                                                   int* __restrict__ part,
                                                   int* __restrict__ bsum) {
    const int i = blockIdx.x * 256 + threadIdx.x;
    const int lane = threadIdx.x & 63;
    const int wid = threadIdx.x >> 6;
    const int v = (i < N_NODES) ? cnt_i[i] : 0;
    int s = v;
#pragma unroll
    for (int d = 1; d < 64; d <<= 1) {
        int t = __shfl_up(s, d, 64);
        if (lane >= d) s += t;
    }
    __shared__ int wsum[4];
    if (lane == 63) wsum[wid] = s;
    __syncthreads();
    int woff = 0;
    for (int w = 0; w < wid; ++w) woff += wsum[w];
    if (i < N_NODES) part[i] = s - v + woff;
    if (threadIdx.x == 255) bsum[blockIdx.x] = woff + s;  // block total
}

// ---------------------------------------------------------------------------
// CSR build step 2b: exclusive scan of the 196 block totals (single block).
// Also computes w2 (tiny, independent) to keep it off other kernels.
// ---------------------------------------------------------------------------
__global__ __launch_bounds__(256) void k_scan_tops(const int* __restrict__ bsum,
                                                   int* __restrict__ boff,
                                                   const float* __restrict__ basis2,
                                                   const float* __restrict__ comp2,
                                                   float* __restrict__ w2) {
    const int NB = (N_NODES + 255) / 256;  // 196
    const int lane = threadIdx.x & 63;
    const int wid = threadIdx.x >> 6;
    const int v = (threadIdx.x < NB) ? bsum[threadIdx.x] : 0;
    int s = v;
#pragma unroll
    for (int d = 1; d < 64; d <<= 1) {
        int t = __shfl_up(s, d, 64);
        if (lane >= d) s += t;
    }
    __shared__ int wsum[4];
    if (lane == 63) wsum[wid] = s;
    __syncthreads();
    int woff = 0;
    for (int w = 0; w < wid; ++w) woff += wsum[w];
    if (threadIdx.x < NB) boff[threadIdx.x] = s - v + woff;

    // w2[r][h][c] = sum_b comp2[r][b] * basis2[b][h][c]   (3200 outputs)
    const int HC = H_DIM * C_DIM;  // 64
    for (int idx = threadIdx.x; idx < R_REL * HC; idx += 256) {
        const int r = idx / HC;
        const int hc = idx % HC;
        float acc = 0.f;
#pragma unroll
        for (int b = 0; b < B_BAS; ++b)
            acc += comp2[r * B_BAS + b] * basis2[b * HC + hc];
        w2[idx] = acc;
    }
}

// ---------------------------------------------------------------------------
// CSR build step 2c: combine -> off[] and a working cursor[] copy
// ---------------------------------------------------------------------------
__global__ __launch_bounds__(256) void k_scan_add(const int* __restrict__ part,
                                                  const int* __restrict__ boff,
                                                  int* __restrict__ off,
                                                  int* __restrict__ cursor) {
    const int i = blockIdx.x * 256 + threadIdx.x;
    if (i < N_NODES) {
        const int o = part[i] + boff[blockIdx.x];
        off[i] = o;
        cursor[i] = o;
    }
    if (i == 0) off[N_NODES] = E_EDGES;
}

// ---------------------------------------------------------------------------
// CSR build step 3 (XCD-sliced): scatter packed (src | et<<16) records into
// dst buckets. blockIdx = chunk*8 + slice; a block only handles edges whose
// dst is in its slice's 6250-node range (blockIdx%8 ~ XCD -> rec slice writes
// coalesce in one XCD's L2). Streaming ei/et reads are non-temporal so they
// don't evict the dirty rec lines before neighbors coalesce into them.
// ---------------------------------------------------------------------------
__global__ __launch_bounds__(256) void k_bucket(const int* __restrict__ ei,
                                                const int* __restrict__ et,
                                                int* __restrict__ cursor,
                                                unsigned* __restrict__ rec) {
    const int chunk = blockIdx.x >> 3;
    const int slice = blockIdx.x & (NSLICE - 1);
    const int lo = slice * SLICE_NODES;

    const int e = chunk * 256 + threadIdx.x;
    if (e >= E_EDGES) return;
    const int dst = __builtin_nontemporal_load(&ei[E_EDGES + e]);
    if ((unsigned)(dst - lo) >= (unsigned)SLICE_NODES) return;

    const int src = __builtin_nontemporal_load(&ei[e]);
    const int r = __builtin_nontemporal_load(&et[e]);
    const int pos = atomicAdd(&cursor[dst], 1);
    rec[pos] = (unsigned)src | ((unsigned)r << 16);
}

// ---------------------------------------------------------------------------
// k_agg1x: atomic-free layer-1 aggregation fused with x-epilogue.
// One wave per dst; lanes = (sub=lane>>4) edge-slot x (h=lane&15).
// BATCH-4 GATHER PIPELINE: prefetch 4 rec entries (independent loads issue
// together), then issue all 4 w1 gathers back-to-back. Breaks the serial
// rec->gather chain: batch cost ~ rec_lat + w1_lat instead of 4x(sum).
// ---------------------------------------------------------------------------
__global__ __launch_bounds__(256) void k_agg1x(const unsigned* __restrict__ rec,
                                               const int* __restrict__ off,
                                               const float* __restrict__ w1,
                                               const float* __restrict__ root1,
                                               const float* __restrict__ bias1,
                                               float* __restrict__ x) {
    const int wid = threadIdx.x >> 6;
    const int lane = threadIdx.x & 63;
    const int dst = blockIdx.x * 4 + wid;   // grid = 12500, 4 waves/block
    const int h = lane & 15;
    const int sub = lane >> 4;
    const int e0 = off[dst], e1 = off[dst + 1];

    float acc = 0.f;
    for (int e = e0 + sub; e < e1; e += 16) {
        unsigned p[4];
#pragma unroll
        for (int j = 0; j < 4; ++j) {
            const int ej = e + j * 4;
            p[j] = (ej < e1) ? rec[ej] : 0xFFFFFFFFu;
        }
#pragma unroll
        for (int j = 0; j < 4; ++j) {
            if (p[j] != 0xFFFFFFFFu) {
                const int src = (int)(p[j] & 0xFFFFu);
                const int r = (int)(p[j] >> 16);
                acc += w1[(size_t)r * NH + src * H_DIM + h];
            }
        }
    }
    acc += __shfl_xor(acc, 16, 64);
    acc += __shfl_xor(acc, 32, 64);

    if (sub == 0) {
        const float c = fmaxf((float)(e1 - e0), 1.f);
        const float v = acc / c + root1[dst * H_DIM + h] + bias1[h];
        x[dst * H_DIM + h] = fmaxf(v, 0.f);
    }
}

// ---------------------------------------------------------------------------
// k_agg2out: atomic-free layer-2 aggregation fused with root2 matvec and
// log_softmax. One wave per dst; batch-4 pipelined like k_agg1x.
// ---------------------------------------------------------------------------
__global__ __launch_bounds__(256) void k_agg2out(const unsigned* __restrict__ rec,
                                                 const int* __restrict__ off,
                                                 const float* __restrict__ x,
                                                 const float* __restrict__ w2,
                                                 const float* __restrict__ root2,
                                                 const float* __restrict__ bias2,
                                                 float* __restrict__ out) {
    const int wid = threadIdx.x >> 6;
    const int lane = threadIdx.x & 63;
    const int dst = blockIdx.x * 4 + wid;
    const int h = lane & 15;
    const int sub = lane >> 4;
    const int e0 = off[dst], e1 = off[dst + 1];

    float a0 = 0.f, a1 = 0.f, a2 = 0.f, a3 = 0.f;
    for (int e = e0 + sub; e < e1; e += 16) {
        unsigned p[4];
#pragma unroll
        for (int j = 0; j < 4; ++j) {
            const int ej = e + j * 4;
            p[j] = (ej < e1) ? rec[ej] : 0xFFFFFFFFu;
        }
#pragma unroll
        for (int j = 0; j < 4; ++j) {
            if (p[j] != 0xFFFFFFFFu) {
                const int src = (int)(p[j] & 0xFFFFu);
                const int r = (int)(p[j] >> 16);
                const float xv = x[src * H_DIM + h];
                const float4 w = *(const float4*)(w2 + r * (H_DIM * C_DIM) + h * C_DIM);
                a0 += xv * w.x; a1 += xv * w.y; a2 += xv * w.z; a3 += xv * w.w;
            }
        }
    }
    // reduce over all 64 lanes (sums over both h and edge-slot)
#pragma unroll
    for (int d = 1; d < 64; d <<= 1) {
        a0 += __shfl_xor(a0, d, 64);
        a1 += __shfl_xor(a1, d, 64);
        a2 += __shfl_xor(a2, d, 64);
        a3 += __shfl_xor(a3, d, 64);
    }

    if (lane == 0) {
        const float c = fmaxf((float)(e1 - e0), 1.f);
        float y0 = a0 / c + bias2[0];
        float y1 = a1 / c + bias2[1];
        float y2 = a2 / c + bias2[2];
        float y3 = a3 / c + bias2[3];
#pragma unroll
        for (int hh = 0; hh < H_DIM; ++hh) {
            const float xv = x[dst * H_DIM + hh];
            const float4 w = *(const float4*)(root2 + hh * C_DIM);
            y0 += xv * w.x; y1 += xv * w.y; y2 += xv * w.z; y3 += xv * w.w;
        }
        const float m = fmaxf(fmaxf(y0, y1), fmaxf(y2, y3));
        const float s = expf(y0 - m) + expf(y1 - m) + expf(y2 - m) + expf(y3 - m);
        const float lse = m + logf(s);
        out[dst * 4 + 0] = y0 - lse;
        out[dst * 4 + 1] = y1 - lse;
        out[dst * 4 + 2] = y2 - lse;
        out[dst * 4 + 3] = y3 - lse;
    }
}

// ---------------------------------------------------------------------------
extern "C" void kernel_launch(void* const* d_in, const int* in_sizes, int n_in,
                              void* d_out, int out_size, void* d_ws, size_t ws_size,
                              hipStream_t stream) {
    const int*   edge_index = (const int*)d_in[0];   // [2, E]
    const int*   edge_type  = (const int*)d_in[1];   // [E]
    // d_in[2] = edge_norm (unused by reference)
    const float* basis1 = (const float*)d_in[3];     // [B, N, H]
    const float* comp1  = (const float*)d_in[4];     // [R, B]
    const float* root1  = (const float*)d_in[5];     // [N, H]
    const float* bias1  = (const float*)d_in[6];     // [H]
    const float* basis2 = (const float*)d_in[7];     // [B, H, C]
    const float* comp2  = (const float*)d_in[8];     // [R, B]
    const float* root2  = (const float*)d_in[9];     // [H, C]
    const float* bias2  = (const float*)d_in[10];    // [C]

    float* out = (float*)d_out;

    // ---- workspace layout (16B aligned blocks) ----
    char* ws = (char*)d_ws;
    size_t o = 0;
    auto take = [&](size_t bytes) { char* p = ws + o; o += (bytes + 15) & ~(size_t)15; return p; };

    float*    w1     = (float*)   take((size_t)R_REL * NH * sizeof(float));   // 160.0 MB
    unsigned* rec    = (unsigned*)take((size_t)E_EDGES * sizeof(unsigned));   //   6.4 MB
    float*    x      = (float*)   take((size_t)NH * sizeof(float));           //   3.2 MB
    int*      part   = (int*)x;   // alias: part dead before x is written
    int*      off    = (int*)     take((size_t)(N_NODES + 1) * sizeof(int));
    int*      cnt_i  = (int*)     take((size_t)N_NODES * sizeof(int));
    int*      cursor = (int*)     take((size_t)N_NODES * sizeof(int));
    float*    w2     = (float*)   take((size_t)R_REL * H_DIM * C_DIM * sizeof(float));
    int*      bsum   = (int*)     take(256 * sizeof(int));
    int*      boff   = (int*)     take(256 * sizeof(int));
    (void)ws_size;

    const int NB = (N_NODES + 255) / 256;  // 196 scan blocks

    // zero the histogram (ws is poisoned 0xAA before every timed call)
    hipMemsetAsync(cnt_i, 0, (size_t)N_NODES * sizeof(int), stream);

    // fused front-end: every block does hist share + w1 share
    k_front<<<FRONT_BLOCKS, 256, 0, stream>>>(basis1, comp1, w1, edge_index, cnt_i);

    // CSR build: scan (+w2 piggyback) -> bucket (XCD-sliced scatter)
    k_scan_part<<<NB, 256, 0, stream>>>(cnt_i, part, bsum);
    k_scan_tops<<<1, 256, 0, stream>>>(bsum, boff, basis2, comp2, w2);
    k_scan_add<<<NB, 256, 0, stream>>>(part, boff, off, cursor);
    {
        const int chunks = (E_EDGES + 255) / 256;  // 6250
        k_bucket<<<chunks * NSLICE, 256, 0, stream>>>(edge_index, edge_type, cursor, rec);
    }

    // layer 1 (atomic-free, batch-4 pipelined) fused with relu/root/bias
    k_agg1x<<<N_NODES / 4, 256, 0, stream>>>(rec, off, w1, root1, bias1, x);

    // layer 2 (atomic-free, batch-4 pipelined) fused with root2 + log_softmax
    k_agg2out<<<N_NODES / 4, 256, 0, stream>>>(rec, off, x, w2, root2, bias2, out);
}